// Round 1
// baseline (5496.755 us; speedup 1.0000x reference)
//
#include <hip/hip_runtime.h>

#define HID 128
#define NT 8
#define ET 64      // edges per tile in msg kernel
#define NTILE 32   // nodes per tile in GRU kernel

// ---------------- edge bucketing by type ----------------
__global__ void hist_kernel(const int* __restrict__ etype, int E, int* __restrict__ counts) {
    __shared__ int lc[NT];
    if (threadIdx.x < NT) lc[threadIdx.x] = 0;
    __syncthreads();
    int stride = gridDim.x * blockDim.x;
    for (int i = blockIdx.x * blockDim.x + threadIdx.x; i < E; i += stride)
        atomicAdd(&lc[etype[i]], 1);
    __syncthreads();
    if (threadIdx.x < NT) atomicAdd(&counts[threadIdx.x], lc[threadIdx.x]);
}

__global__ void scan_kernel(const int* __restrict__ counts, int* __restrict__ cursor) {
    if (threadIdx.x == 0 && blockIdx.x == 0) {
        int off = 0;
        for (int t = 0; t < NT; ++t) {
            cursor[t] = off;
            off += (counts[t] + ET - 1) & ~(ET - 1);   // 64-align each bucket
        }
    }
}

__global__ void scatter_kernel(const int* __restrict__ etype, int E,
                               int* __restrict__ cursor, int* __restrict__ sorted) {
    int stride = gridDim.x * blockDim.x;
    for (int i = blockIdx.x * blockDim.x + threadIdx.x; i < E; i += stride) {
        int t = etype[i];
        int pos = atomicAdd(&cursor[t], 1);
        sorted[pos] = i;
    }
}

// ---------------- per-edge-type message GEMM + scatter-add ----------------
// tile: 64 edges x 128 out-dims, all edges in a tile share one type (aligned buckets).
// msg[dst[e]][d] += sum_k h[src[e]][k] * W[t][k][d] + b[t][d]
__global__ __launch_bounds__(128) void msg_kernel(
    const float* __restrict__ h, const int* __restrict__ ei, int E,
    const int* __restrict__ etype,
    const float* __restrict__ W, const float* __restrict__ b,
    const int* __restrict__ sorted,
    float* __restrict__ msg)
{
    __shared__ float hs[ET][132];   // gathered h rows, +4 pad (16B-aligned rows)
    __shared__ float wt[HID][36];   // W chunk transposed: wt[d][kk], kk in [0,32)
    __shared__ int srcs[ET];
    __shared__ int dsts[ET];
    __shared__ int stype;

    int tx = threadIdx.x;
    int base = blockIdx.x * ET;

    if (tx < ET) {
        int id = sorted[base + tx];
        srcs[tx] = (id >= 0) ? ei[id] : -1;
        dsts[tx] = (id >= 0) ? ei[E + id] : -1;
        if (tx == 0) stype = (id >= 0) ? etype[id] : -1;
    }
    __syncthreads();
    int t = stype;
    if (t < 0) return;                 // fully-padded tile

    // stage gathered h rows (coalesced over k)
    for (int i = tx; i < ET * HID; i += 128) {
        int e = i >> 7, k = i & 127;
        int s = srcs[e];
        hs[e][k] = (s >= 0) ? h[s * HID + k] : 0.0f;
    }

    const float* Wt = W + t * HID * HID;   // W[t][k][d] row-major
    int tcol = tx & 15;   // d = tcol + 16*i   (i<8) — interleaved to dodge bank conflicts
    int trow = tx >> 4;   // e = trow + 8*j    (j<8)

    float acc[8][8];
    #pragma unroll
    for (int j = 0; j < 8; ++j)
        #pragma unroll
        for (int i = 0; i < 8; ++i) acc[j][i] = 0.0f;

    for (int kc = 0; kc < 4; ++kc) {
        __syncthreads();
        // stage transposed W chunk: wt[d][kk] = Wt[(kc*32+kk)*HID + d] (coalesced global read)
        for (int i = tx; i < HID * 32; i += 128) {
            int d = i & 127, kk = i >> 7;
            wt[d][kk] = Wt[(kc * 32 + kk) * HID + d];
        }
        __syncthreads();
        #pragma unroll
        for (int kk = 0; kk < 32; kk += 4) {
            float4 wv[8], hv[8];
            #pragma unroll
            for (int i = 0; i < 8; ++i) wv[i] = *(const float4*)&wt[tcol + 16 * i][kk];
            #pragma unroll
            for (int j = 0; j < 8; ++j) hv[j] = *(const float4*)&hs[trow + 8 * j][kc * 32 + kk];
            #pragma unroll
            for (int j = 0; j < 8; ++j)
                #pragma unroll
                for (int i = 0; i < 8; ++i)
                    acc[j][i] += hv[j].x * wv[i].x + hv[j].y * wv[i].y
                               + hv[j].z * wv[i].z + hv[j].w * wv[i].w;
        }
    }

    // bias + scatter-add
    #pragma unroll
    for (int j = 0; j < 8; ++j) {
        int e = trow + 8 * j;
        int dd = dsts[e];
        if (dd < 0) continue;
        #pragma unroll
        for (int i = 0; i < 8; ++i) {
            int d = tcol + 16 * i;
            atomicAdd(&msg[dd * HID + d], acc[j][i] + b[t * HID + d]);
        }
    }
}

// ---------------- fused GRUCell ----------------
// gi = msg @ w_ih^T + b_ih ; gh = h @ w_hh^T + b_hh (computed gate-chunk by gate-chunk)
__global__ __launch_bounds__(256) void gru_kernel(
    const float* __restrict__ hin, const float* __restrict__ msgin,
    const float* __restrict__ w_ih, const float* __restrict__ w_hh,
    const float* __restrict__ b_ih, const float* __restrict__ b_hh,
    float* __restrict__ out)
{
    __shared__ float ms[NTILE][132];
    __shared__ float hsm[NTILE][132];
    __shared__ float wi[HID][36];
    __shared__ float wh[HID][36];

    int tx = threadIdx.x;
    int n0 = blockIdx.x * NTILE;

    for (int i = tx; i < NTILE * HID; i += 256) {
        int e = i >> 7, k = i & 127;
        ms[e][k]  = msgin[(n0 + e) * HID + k];
        hsm[e][k] = hin[(n0 + e) * HID + k];
    }

    int tcol = tx & 31;   // d = tcol + 32*i  (i<4)
    int trow = tx >> 5;   // e = trow + 8*j   (j<4)

    float r[4][4], z[4][4];

    for (int g = 0; g < 3; ++g) {
        float gi[4][4], gh[4][4];
        #pragma unroll
        for (int j = 0; j < 4; ++j)
            #pragma unroll
            for (int i = 0; i < 4; ++i) { gi[j][i] = 0.f; gh[j][i] = 0.f; }

        for (int kc = 0; kc < 4; ++kc) {
            __syncthreads();
            // stage weight k-chunks for this gate: rows g*128+d, cols kc*32+kk
            for (int i = tx; i < HID * 32; i += 256) {
                int d = i >> 5, kk = i & 31;
                wi[d][kk] = w_ih[(g * HID + d) * HID + kc * 32 + kk];
                wh[d][kk] = w_hh[(g * HID + d) * HID + kc * 32 + kk];
            }
            __syncthreads();
            #pragma unroll
            for (int kk = 0; kk < 32; kk += 4) {
                float4 wvi[4], wvh[4], mv[4], hv[4];
                #pragma unroll
                for (int i = 0; i < 4; ++i) {
                    wvi[i] = *(const float4*)&wi[tcol + 32 * i][kk];
                    wvh[i] = *(const float4*)&wh[tcol + 32 * i][kk];
                }
                #pragma unroll
                for (int j = 0; j < 4; ++j) {
                    mv[j] = *(const float4*)&ms[trow + 8 * j][kc * 32 + kk];
                    hv[j] = *(const float4*)&hsm[trow + 8 * j][kc * 32 + kk];
                }
                #pragma unroll
                for (int j = 0; j < 4; ++j)
                    #pragma unroll
                    for (int i = 0; i < 4; ++i) {
                        gi[j][i] += mv[j].x*wvi[i].x + mv[j].y*wvi[i].y + mv[j].z*wvi[i].z + mv[j].w*wvi[i].w;
                        gh[j][i] += hv[j].x*wvh[i].x + hv[j].y*wvh[i].y + hv[j].z*wvh[i].z + hv[j].w*wvh[i].w;
                    }
            }
        }
        // bias + gate nonlinearity
        #pragma unroll
        for (int i = 0; i < 4; ++i) {
            int d = tcol + 32 * i;
            float bi = b_ih[g * HID + d];
            float bh = b_hh[g * HID + d];
            #pragma unroll
            for (int j = 0; j < 4; ++j) {
                float a = gi[j][i] + bi;
                float hterm = gh[j][i] + bh;
                if (g == 0)      r[j][i] = 1.f / (1.f + __expf(-(a + hterm)));
                else if (g == 1) z[j][i] = 1.f / (1.f + __expf(-(a + hterm)));
                else {
                    float nn = tanhf(a + r[j][i] * hterm);
                    int e = trow + 8 * j;
                    float h0 = hsm[e][d];
                    out[(n0 + e) * HID + d] = (1.f - z[j][i]) * nn + z[j][i] * h0;
                }
            }
        }
    }
}

extern "C" void kernel_launch(void* const* d_in, const int* in_sizes, int n_in,
                              void* d_out, int out_size, void* d_ws, size_t ws_size,
                              hipStream_t stream)
{
    const float* h     = (const float*)d_in[0];
    const int*   ei    = (const int*)d_in[1];   // [2,E]: src row then dst row
    const int*   etype = (const int*)d_in[2];
    const float* W     = (const float*)d_in[3]; // (T, H_in, H_out)
    const float* b     = (const float*)d_in[4];
    const float* w_ih  = (const float*)d_in[5]; // (3H, H)
    const float* w_hh  = (const float*)d_in[6];
    const float* b_ih  = (const float*)d_in[7];
    const float* b_hh  = (const float*)d_in[8];
    float* out = (float*)d_out;

    int E = in_sizes[1] / 2;
    int N = in_sizes[0] / HID;

    int* counts = (int*)d_ws;               // NT
    int* cursor = counts + NT;              // NT
    int* sorted = cursor + NT;              // E + NT*ET slots
    int sortedCap = ((E + ET - 1) / ET + NT) * ET;

    hipMemsetAsync(counts, 0, NT * sizeof(int), stream);
    hipMemsetAsync(sorted, 0xFF, (size_t)sortedCap * sizeof(int), stream);  // -1 fill
    hipMemsetAsync(out, 0, (size_t)N * HID * sizeof(float), stream);        // msg accumulator

    hist_kernel<<<512, 256, 0, stream>>>(etype, E, counts);
    scan_kernel<<<1, 64, 0, stream>>>(counts, cursor);
    scatter_kernel<<<512, 256, 0, stream>>>(etype, E, cursor, sorted);

    int ntiles = sortedCap / ET;
    msg_kernel<<<ntiles, 128, 0, stream>>>(h, ei, E, etype, W, b, sorted, out);
    // messages live in d_out; GRU reads them (staged to LDS first) and overwrites with h'
    gru_kernel<<<N / NTILE, 256, 0, stream>>>(h, out, w_ih, w_hh, b_ih, b_hh, out);
}

// Round 3
// 2807.356 us; speedup vs baseline: 1.9580x; 1.9580x over previous
//
#include <hip/hip_runtime.h>

#define HID 128
#define NTY 8

typedef __attribute__((ext_vector_type(8))) short bf16x8;
typedef __attribute__((ext_vector_type(4))) float f32x4;

__device__ __forceinline__ unsigned short f2bf(float x) {
    unsigned u = __float_as_uint(x);
    u += 0x7FFF + ((u >> 16) & 1);          // RNE
    return (unsigned short)(u >> 16);
}
__device__ __forceinline__ float bf2f(unsigned short s) {
    return __uint_as_float(((unsigned)s) << 16);
}

// ---------------- dtype prep ----------------
__global__ void conv_h_kernel(const float* __restrict__ h, unsigned short* __restrict__ hbf, int n) {
    int i = blockIdx.x * 256 + threadIdx.x;
    if (i < n) hbf[i] = f2bf(h[i]);
}
// WbfT[t][d][k] = bf16(W[t][k][d])  (B^T layout for MFMA B-frag b128 reads)
__global__ void conv_W_kernel(const float* __restrict__ W, unsigned short* __restrict__ WbfT) {
    int i = blockIdx.x * 256 + threadIdx.x;   // 8*128*128
    int t = i >> 14, rem = i & 16383, d = rem >> 7, k = rem & 127;
    WbfT[(t << 14) + (d << 7) + k] = f2bf(W[(t << 14) + (k << 7) + d]);
}
// wcat[c][k], c in [0,512): gate-major concat of GRU weights (transposed), zero-padded
__global__ void conv_wcat_kernel(const float* __restrict__ wih, const float* __restrict__ whh,
                                 unsigned short* __restrict__ wcat) {
    int i = blockIdx.x * 256 + threadIdx.x;   // 512*256
    int c = i >> 8, k = i & 255;
    int g = c >> 7, d = c & 127;
    float v = 0.f;
    if (g < 2)       v = (k < 128) ? wih[(g * 128 + d) * 128 + k] : whh[(g * 128 + d) * 128 + (k - 128)];
    else if (g == 2) { if (k < 128)  v = wih[(256 + d) * 128 + k]; }
    else             { if (k >= 128) v = whh[(256 + d) * 128 + (k - 128)]; }
    wcat[c * 256 + k] = f2bf(v);
}

// ---------------- sort bookkeeping ----------------
__global__ void hist_kernel(const int* __restrict__ etype, const int* __restrict__ ei,
                            int E, int* __restrict__ tcnt, int* __restrict__ deg) {
    __shared__ int lc[NTY];
    if (threadIdx.x < NTY) lc[threadIdx.x] = 0;
    __syncthreads();
    int stride = gridDim.x * blockDim.x;
    for (int i = blockIdx.x * blockDim.x + threadIdx.x; i < E; i += stride) {
        atomicAdd(&lc[etype[i]], 1);
        if (deg) atomicAdd(&deg[ei[E + i]], 1);
    }
    __syncthreads();
    if (threadIdx.x < NTY) atomicAdd(&tcnt[threadIdx.x], lc[threadIdx.x]);
}

__global__ void scan_type_kernel(const int* __restrict__ tcnt, int* __restrict__ tcur) {
    if (threadIdx.x == 0) {
        int off = 0;
        for (int t = 0; t < NTY; ++t) { tcur[t] = off; off += (tcnt[t] + 127) & ~127; }
    }
}

__global__ void scanA_kernel(const int* __restrict__ deg, int* __restrict__ start,
                             int* __restrict__ bsum, int N) {
    __shared__ int s[256];
    int i = blockIdx.x * 256 + threadIdx.x;
    int v = (i < N) ? deg[i] : 0;
    s[threadIdx.x] = v;
    __syncthreads();
    for (int off = 1; off < 256; off <<= 1) {
        int t = (threadIdx.x >= off) ? s[threadIdx.x - off] : 0;
        __syncthreads();
        s[threadIdx.x] += t;
        __syncthreads();
    }
    if (i < N) start[i] = s[threadIdx.x] - v;
    if (threadIdx.x == 255) bsum[blockIdx.x] = s[255];
}

__global__ void scanB_kernel(int* __restrict__ bsum, int nb) {
    __shared__ int s[512];
    int tx = threadIdx.x;
    int v = (tx < nb) ? bsum[tx] : 0;
    s[tx] = v;
    __syncthreads();
    for (int off = 1; off < 512; off <<= 1) {
        int t = (tx >= off) ? s[tx - off] : 0;
        __syncthreads();
        s[tx] += t;
        __syncthreads();
    }
    if (tx < nb) bsum[tx] = s[tx] - v;
}

__global__ void scanC_kernel(int* __restrict__ start, const int* __restrict__ bsum,
                             int* __restrict__ dcur, int N, int E) {
    int i = blockIdx.x * 256 + threadIdx.x;
    if (i < N) {
        int v = start[i] + bsum[blockIdx.x];
        start[i] = v;
        dcur[i] = v;
    }
    if (i == 0) start[N] = E;
}

__global__ void scatter_kernel(const int* __restrict__ etype, const int* __restrict__ ei,
                               int E, int* __restrict__ tcur, int* __restrict__ dcur,
                               int* __restrict__ sortedT, int* __restrict__ q, int mode) {
    int stride = gridDim.x * blockDim.x;
    for (int i = blockIdx.x * blockDim.x + threadIdx.x; i < E; i += stride) {
        int pos = atomicAdd(&tcur[etype[i]], 1);
        sortedT[pos] = i;
        if (mode) q[i] = atomicAdd(&dcur[ei[E + i]], 1);
    }
}

// ---------------- msg GEMM: 128-edge x 128-d tile, bf16 MFMA ----------------
// mode==0: store per-edge rows to dst-sorted M[q[e]] (bf16)
// mode==1: fp32 atomicAdd into msum[dst] (fallback path, no M buffer)
__global__ __launch_bounds__(256) void msg_gemm(
    const unsigned short* __restrict__ hbf, const int* __restrict__ ei, int E,
    const int* __restrict__ etype, const unsigned short* __restrict__ WbfT,
    const float* __restrict__ bias, const int* __restrict__ sortedT,
    const int* __restrict__ q, unsigned short* __restrict__ M,
    float* __restrict__ msum, int mode)
{
    __shared__ unsigned short hs[128][136];
    __shared__ unsigned short Bs[128][40];
    __shared__ int srcs[128], aux[128];
    __shared__ int stype;

    int tx = threadIdx.x;
    int base = blockIdx.x * 128;
    if (tx < 128) {
        int id = sortedT[base + tx];
        srcs[tx] = (id >= 0) ? ei[id] : -1;
        aux[tx]  = (id >= 0) ? (mode ? ei[E + id] : q[id]) : -1;
    }
    if (tx == 0) { int id0 = sortedT[base]; stype = (id0 >= 0) ? etype[id0] : -1; }
    __syncthreads();
    int t = stype;
    if (t < 0) return;

    const unsigned short* Wb = WbfT + (t << 14);

    for (int f = tx; f < 2048; f += 256) {
        int row = f >> 4, c8 = (f & 15) * 8;
        int s = srcs[row]; if (s < 0) s = 0;
        *(uint4*)&hs[row][c8] = *(const uint4*)&hbf[(size_t)s * 128 + c8];
    }

    int lane = tx & 63, w = tx >> 6;
    int r0 = (w >> 1) * 64, c0 = (w & 1) * 64;
    int lr = lane & 15, quad = lane >> 4;
    f32x4 acc[4][4] = {};

    for (int kc = 0; kc < 4; ++kc) {
        __syncthreads();
        for (int f = tx; f < 512; f += 256) {
            int d = f >> 2, c8 = (f & 3) * 8;
            *(uint4*)&Bs[d][c8] = *(const uint4*)&Wb[(d << 7) + kc * 32 + c8];
        }
        __syncthreads();
        bf16x8 af[4], bfr[4];
        #pragma unroll
        for (int rb = 0; rb < 4; ++rb) af[rb]  = *(const bf16x8*)&hs[r0 + rb * 16 + lr][kc * 32 + quad * 8];
        #pragma unroll
        for (int cb = 0; cb < 4; ++cb) bfr[cb] = *(const bf16x8*)&Bs[c0 + cb * 16 + lr][quad * 8];
        #pragma unroll
        for (int rb = 0; rb < 4; ++rb)
            #pragma unroll
            for (int cb = 0; cb < 4; ++cb)
                acc[rb][cb] = __builtin_amdgcn_mfma_f32_16x16x32_bf16(af[rb], bfr[cb], acc[rb][cb], 0, 0, 0);
    }

    #pragma unroll
    for (int cb = 0; cb < 4; ++cb) {
        int d = c0 + cb * 16 + lr;
        float bv = bias[t * 128 + d];
        #pragma unroll
        for (int rb = 0; rb < 4; ++rb) {
            #pragma unroll
            for (int reg = 0; reg < 4; ++reg) {
                int e = r0 + rb * 16 + quad * 4 + reg;
                int dd = aux[e];
                if (dd < 0) continue;
                float v = acc[rb][cb][reg] + bv;
                if (mode) atomicAdd(&msum[(size_t)dd * 128 + d], v);
                else      M[(size_t)dd * 128 + d] = f2bf(v);
            }
        }
    }
}

// ---------------- segment reduce: sum each node's contiguous M rows -> fp32 msum ----------------
__global__ __launch_bounds__(256) void reduce_seg(
    const unsigned short* __restrict__ M, const int* __restrict__ start,
    float* __restrict__ msum, int N)
{
    int node = blockIdx.x * 2 + (threadIdx.x >> 7);
    int d = threadIdx.x & 127;
    if (node >= N) return;
    int s = start[node], e = start[node + 1];
    float acc = 0.f;
    for (int r = s; r < e; ++r) acc += bf2f(M[(size_t)r * 128 + d]);
    msum[(size_t)node * 128 + d] = acc;
}

// ---------------- fused GRU: 32 nodes/block, all 512 gate cols, K=256, no G buffer ----------------
__global__ __launch_bounds__(256) void gru_fused(
    const float* __restrict__ msum, const unsigned short* __restrict__ hbf,
    const unsigned short* __restrict__ wcat, const float* __restrict__ bih,
    const float* __restrict__ bhh, const float* __restrict__ hf,
    float* __restrict__ out, int N)
{
    __shared__ unsigned short As[32][264];   // [node][k]: k<128 = m (bf16 of msum), k>=128 = h
    __shared__ unsigned short Bs[512][40];   // wcat k-chunk

    int tx = threadIdx.x;
    int n0 = blockIdx.x * 32;

    for (int f = tx; f < 1024; f += 256) {
        int row = f >> 5, c4 = (f & 31) * 4;
        int n = n0 + row; if (n >= N) n = N - 1;
        float4 v = *(const float4*)&msum[(size_t)n * 128 + c4];
        As[row][c4 + 0] = f2bf(v.x); As[row][c4 + 1] = f2bf(v.y);
        As[row][c4 + 2] = f2bf(v.z); As[row][c4 + 3] = f2bf(v.w);
    }
    for (int f = tx; f < 512; f += 256) {
        int row = f >> 4, c8 = (f & 15) * 8;
        int n = n0 + row; if (n >= N) n = N - 1;
        *(uint4*)&As[row][128 + c8] = *(const uint4*)&hbf[(size_t)n * 128 + c8];
    }

    int lane = tx & 63, w = tx >> 6;
    int rt = w & 1, cg = w >> 1;     // row tile (of 2), col group (of 2)
    int lr = lane & 15, quad = lane >> 4;
    f32x4 acc[4][4] = {};            // [gate][cb]

    for (int kc = 0; kc < 8; ++kc) {
        __syncthreads();
        for (int f = tx; f < 2048; f += 256) {
            int c = f >> 2, c8 = (f & 3) * 8;
            *(uint4*)&Bs[c][c8] = *(const uint4*)&wcat[(size_t)c * 256 + kc * 32 + c8];
        }
        __syncthreads();
        bf16x8 af = *(const bf16x8*)&As[rt * 16 + lr][kc * 32 + quad * 8];
        #pragma unroll
        for (int g = 0; g < 4; ++g)
            #pragma unroll
            for (int cb = 0; cb < 4; ++cb) {
                bf16x8 bf = *(const bf16x8*)&Bs[g * 128 + cg * 64 + cb * 16 + lr][quad * 8];
                acc[g][cb] = __builtin_amdgcn_mfma_f32_16x16x32_bf16(af, bf, acc[g][cb], 0, 0, 0);
            }
    }

    #pragma unroll
    for (int cb = 0; cb < 4; ++cb) {
        int d = cg * 64 + cb * 16 + lr;           // within-gate column
        float b_r  = bih[d] + bhh[d];
        float b_z  = bih[128 + d] + bhh[128 + d];
        float b_in = bih[256 + d];
        float b_hn = bhh[256 + d];
        #pragma unroll
        for (int reg = 0; reg < 4; ++reg) {
            int n = n0 + rt * 16 + quad * 4 + reg;
            if (n >= N) continue;
            float r  = 1.f / (1.f + __expf(-(acc[0][cb][reg] + b_r)));
            float z  = 1.f / (1.f + __expf(-(acc[1][cb][reg] + b_z)));
            float nn = tanhf(acc[2][cb][reg] + b_in + r * (acc[3][cb][reg] + b_hn));
            float h0 = hf[(size_t)n * 128 + d];
            out[(size_t)n * 128 + d] = (1.f - z) * nn + z * h0;
        }
    }
}

extern "C" void kernel_launch(void* const* d_in, const int* in_sizes, int n_in,
                              void* d_out, int out_size, void* d_ws, size_t ws_size,
                              hipStream_t stream)
{
    const float* h     = (const float*)d_in[0];
    const int*   ei    = (const int*)d_in[1];
    const int*   etype = (const int*)d_in[2];
    const float* W     = (const float*)d_in[3];
    const float* b     = (const float*)d_in[4];
    const float* wih   = (const float*)d_in[5];
    const float* whh   = (const float*)d_in[6];
    const float* bih   = (const float*)d_in[7];
    const float* bhh   = (const float*)d_in[8];
    float* out = (float*)d_out;

    int E = in_sizes[1] / 2;
    int N = in_sizes[0] / HID;
    int capE = ((E + 127) / 128 + NTY) * 128;

    char* p = (char*)d_ws;
    auto alloc = [&](size_t bytes) { char* r = p; p += (bytes + 255) & ~(size_t)255; return r; };
    // base (both paths): ~29 MB
    unsigned short* hbf  = (unsigned short*)alloc((size_t)N * 128 * 2);
    unsigned short* WbfT = (unsigned short*)alloc((size_t)8 * 128 * 128 * 2);
    unsigned short* wcat = (unsigned short*)alloc((size_t)512 * 256 * 2);
    int* tcnt    = (int*)alloc(NTY * 4);
    int* tcur    = (int*)alloc(NTY * 4);
    int* sortedT = (int*)alloc((size_t)capE * 4);
    // fast-path extras: ~157 MB
    unsigned short* M = (unsigned short*)alloc((size_t)E * 128 * 2);
    int* q     = (int*)alloc((size_t)E * 4);
    int* deg   = (int*)alloc((size_t)N * 4);
    int* start = (int*)alloc((size_t)(N + 1) * 4);
    int* dcur  = (int*)alloc((size_t)N * 4);
    int* bsum  = (int*)alloc(512 * 4);
    int mode = ((size_t)(p - (char*)d_ws) <= ws_size) ? 0 : 1;   // 0 = sorted-M path, 1 = atomic fallback

    hipMemsetAsync(tcnt, 0, NTY * 4, stream);
    hipMemsetAsync(sortedT, 0xFF, (size_t)capE * 4, stream);
    if (mode == 0) hipMemsetAsync(deg, 0, (size_t)N * 4, stream);
    else           hipMemsetAsync(out, 0, (size_t)N * 128 * 4, stream);   // msum accumulator

    conv_h_kernel<<<(N * 128 + 255) / 256, 256, 0, stream>>>(h, hbf, N * 128);
    conv_W_kernel<<<(8 * 128 * 128) / 256, 256, 0, stream>>>(W, WbfT);
    conv_wcat_kernel<<<(512 * 256) / 256, 256, 0, stream>>>(wih, whh, wcat);

    hist_kernel<<<1024, 256, 0, stream>>>(etype, ei, E, tcnt, (mode == 0) ? deg : nullptr);
    scan_type_kernel<<<1, 64, 0, stream>>>(tcnt, tcur);
    if (mode == 0) {
        int nbA = (N + 255) / 256;
        scanA_kernel<<<nbA, 256, 0, stream>>>(deg, start, bsum, N);
        scanB_kernel<<<1, 512, 0, stream>>>(bsum, nbA);
        scanC_kernel<<<nbA, 256, 0, stream>>>(start, bsum, dcur, N, E);
    }
    scatter_kernel<<<1024, 256, 0, stream>>>(etype, ei, E, tcur, dcur, sortedT, q, (mode == 0) ? 1 : 0);

    msg_gemm<<<capE / 128, 256, 0, stream>>>(hbf, ei, E, etype, WbfT, b, sortedT, q, M, out, mode);
    if (mode == 0)
        reduce_seg<<<(N + 1) / 2, 256, 0, stream>>>(M, start, out, N);
    // messages (fp32) now live in d_out; gru_fused reads its own 32 rows then overwrites them
    gru_fused<<<(N + 31) / 32, 256, 0, stream>>>(out, hbf, wcat, bih, bhh, h, out, N);
}

// Round 4
// 576.896 us; speedup vs baseline: 9.5282x; 4.8663x over previous
//
#include <hip/hip_runtime.h>

#define HID 128
#define NTY 8

typedef __attribute__((ext_vector_type(8))) short bf16x8;
typedef __attribute__((ext_vector_type(4))) float f32x4;

__device__ __forceinline__ unsigned short f2bf(float x) {
    unsigned u = __float_as_uint(x);
    u += 0x7FFF + ((u >> 16) & 1);          // RNE
    return (unsigned short)(u >> 16);
}
__device__ __forceinline__ float bf2f(unsigned short s) {
    return __uint_as_float(((unsigned)s) << 16);
}

// ---------------- dtype prep ----------------
__global__ void conv_h_kernel(const float* __restrict__ h, unsigned short* __restrict__ hbf, int n) {
    int i = blockIdx.x * 256 + threadIdx.x;
    if (i < n) hbf[i] = f2bf(h[i]);
}
// WbfT[t][d][k] = bf16(W[t][k][d])  (B^T layout for MFMA B-frag b128 reads)
__global__ void conv_W_kernel(const float* __restrict__ W, unsigned short* __restrict__ WbfT) {
    int i = blockIdx.x * 256 + threadIdx.x;   // 8*128*128
    int t = i >> 14, rem = i & 16383, d = rem >> 7, k = rem & 127;
    WbfT[(t << 14) + (d << 7) + k] = f2bf(W[(t << 14) + (k << 7) + d]);
}
// wcat[c][k], c in [0,512): gate-major concat of GRU weights (transposed), zero-padded
__global__ void conv_wcat_kernel(const float* __restrict__ wih, const float* __restrict__ whh,
                                 unsigned short* __restrict__ wcat) {
    int i = blockIdx.x * 256 + threadIdx.x;   // 512*256
    int c = i >> 8, k = i & 255;
    int g = c >> 7, d = c & 127;
    float v = 0.f;
    if (g < 2)       v = (k < 128) ? wih[(g * 128 + d) * 128 + k] : whh[(g * 128 + d) * 128 + (k - 128)];
    else if (g == 2) { if (k < 128)  v = wih[(256 + d) * 128 + k]; }
    else             { if (k >= 128) v = whh[(256 + d) * 128 + (k - 128)]; }
    wcat[c * 256 + k] = f2bf(v);
}

// ---------------- sort bookkeeping ----------------
__global__ void hist_kernel(const int* __restrict__ etype, const int* __restrict__ ei,
                            int E, int* __restrict__ tcnt, int* __restrict__ deg) {
    __shared__ int lc[NTY];
    if (threadIdx.x < NTY) lc[threadIdx.x] = 0;
    __syncthreads();
    int stride = gridDim.x * blockDim.x;
    for (int i = blockIdx.x * blockDim.x + threadIdx.x; i < E; i += stride) {
        atomicAdd(&lc[etype[i]], 1);
        if (deg) atomicAdd(&deg[ei[E + i]], 1);
    }
    __syncthreads();
    if (threadIdx.x < NTY) atomicAdd(&tcnt[threadIdx.x], lc[threadIdx.x]);
}

__global__ void scan_type_kernel(const int* __restrict__ tcnt, int* __restrict__ tcur) {
    if (threadIdx.x == 0) {
        int off = 0;
        for (int t = 0; t < NTY; ++t) { tcur[t] = off; off += (tcnt[t] + 127) & ~127; }
    }
}

__global__ void scanA_kernel(const int* __restrict__ deg, int* __restrict__ start,
                             int* __restrict__ bsum, int N) {
    __shared__ int s[256];
    int i = blockIdx.x * 256 + threadIdx.x;
    int v = (i < N) ? deg[i] : 0;
    s[threadIdx.x] = v;
    __syncthreads();
    for (int off = 1; off < 256; off <<= 1) {
        int t = (threadIdx.x >= off) ? s[threadIdx.x - off] : 0;
        __syncthreads();
        s[threadIdx.x] += t;
        __syncthreads();
    }
    if (i < N) start[i] = s[threadIdx.x] - v;
    if (threadIdx.x == 255) bsum[blockIdx.x] = s[255];
}

__global__ void scanB_kernel(int* __restrict__ bsum, int nb) {
    __shared__ int s[512];
    int tx = threadIdx.x;
    int v = (tx < nb) ? bsum[tx] : 0;
    s[tx] = v;
    __syncthreads();
    for (int off = 1; off < 512; off <<= 1) {
        int t = (tx >= off) ? s[tx - off] : 0;
        __syncthreads();
        s[tx] += t;
        __syncthreads();
    }
    if (tx < nb) bsum[tx] = s[tx] - v;
}

__global__ void scanC_kernel(int* __restrict__ start, const int* __restrict__ bsum,
                             int* __restrict__ dcur, int N, int E) {
    int i = blockIdx.x * 256 + threadIdx.x;
    if (i < N) {
        int v = start[i] + bsum[blockIdx.x];
        start[i] = v;
        dcur[i] = v;
    }
    if (i == 0) start[N] = E;
}

// block-aggregated scatter: 8 global tcur atomics per BLOCK instead of per edge
__global__ __launch_bounds__(256) void scatter_agg(
    const int* __restrict__ etype, const int* __restrict__ ei, int E,
    int* __restrict__ tcur, int* __restrict__ dcur,
    int* __restrict__ sortedT, int* __restrict__ q, int mode)
{
    __shared__ int lcnt[NTY];
    __shared__ int lbase[NTY];
    int tx = threadIdx.x;
    int chunk = (E + gridDim.x - 1) / gridDim.x;
    int s = blockIdx.x * chunk;
    int e = s + chunk; if (e > E) e = E;
    if (tx < NTY) lcnt[tx] = 0;
    __syncthreads();
    for (int i = s + tx; i < e; i += 256)
        atomicAdd(&lcnt[etype[i]], 1);
    __syncthreads();
    if (tx < NTY) {
        lbase[tx] = atomicAdd(&tcur[tx], lcnt[tx]);   // reserve per-type range
        lcnt[tx] = 0;                                  // reuse as local cursor
    }
    __syncthreads();
    for (int i = s + tx; i < e; i += 256) {
        int t = etype[i];
        int lp = atomicAdd(&lcnt[t], 1);              // LDS atomic
        sortedT[lbase[t] + lp] = i;
        if (mode) q[i] = atomicAdd(&dcur[ei[E + i]], 1);  // 100k addrs, low contention
    }
}

// ---------------- msg GEMM: 128-edge x 128-d tile, bf16 MFMA ----------------
// mode==0: store per-edge rows to dst-sorted M[q[e]] (bf16)
// mode==1: fp32 atomicAdd into msum[dst] (fallback path, no M buffer)
__global__ __launch_bounds__(256) void msg_gemm(
    const unsigned short* __restrict__ hbf, const int* __restrict__ ei, int E,
    const int* __restrict__ etype, const unsigned short* __restrict__ WbfT,
    const float* __restrict__ bias, const int* __restrict__ sortedT,
    const int* __restrict__ q, unsigned short* __restrict__ M,
    float* __restrict__ msum, int mode)
{
    __shared__ unsigned short hs[128][136];
    __shared__ unsigned short Bs[128][40];
    __shared__ int srcs[128], aux[128];
    __shared__ int stype;

    int tx = threadIdx.x;
    int base = blockIdx.x * 128;
    if (tx < 128) {
        int id = sortedT[base + tx];
        srcs[tx] = (id >= 0) ? ei[id] : -1;
        aux[tx]  = (id >= 0) ? (mode ? ei[E + id] : q[id]) : -1;
    }
    if (tx == 0) { int id0 = sortedT[base]; stype = (id0 >= 0) ? etype[id0] : -1; }
    __syncthreads();
    int t = stype;
    if (t < 0) return;

    const unsigned short* Wb = WbfT + (t << 14);

    for (int f = tx; f < 2048; f += 256) {
        int row = f >> 4, c8 = (f & 15) * 8;
        int s = srcs[row]; if (s < 0) s = 0;
        *(uint4*)&hs[row][c8] = *(const uint4*)&hbf[(size_t)s * 128 + c8];
    }

    int lane = tx & 63, w = tx >> 6;
    int r0 = (w >> 1) * 64, c0 = (w & 1) * 64;
    int lr = lane & 15, quad = lane >> 4;
    f32x4 acc[4][4] = {};

    for (int kc = 0; kc < 4; ++kc) {
        __syncthreads();
        for (int f = tx; f < 512; f += 256) {
            int d = f >> 2, c8 = (f & 3) * 8;
            *(uint4*)&Bs[d][c8] = *(const uint4*)&Wb[(d << 7) + kc * 32 + c8];
        }
        __syncthreads();
        bf16x8 af[4], bfr[4];
        #pragma unroll
        for (int rb = 0; rb < 4; ++rb) af[rb]  = *(const bf16x8*)&hs[r0 + rb * 16 + lr][kc * 32 + quad * 8];
        #pragma unroll
        for (int cb = 0; cb < 4; ++cb) bfr[cb] = *(const bf16x8*)&Bs[c0 + cb * 16 + lr][quad * 8];
        #pragma unroll
        for (int rb = 0; rb < 4; ++rb)
            #pragma unroll
            for (int cb = 0; cb < 4; ++cb)
                acc[rb][cb] = __builtin_amdgcn_mfma_f32_16x16x32_bf16(af[rb], bfr[cb], acc[rb][cb], 0, 0, 0);
    }

    #pragma unroll
    for (int cb = 0; cb < 4; ++cb) {
        int d = c0 + cb * 16 + lr;
        float bv = bias[t * 128 + d];
        #pragma unroll
        for (int rb = 0; rb < 4; ++rb) {
            #pragma unroll
            for (int reg = 0; reg < 4; ++reg) {
                int e = r0 + rb * 16 + quad * 4 + reg;
                int dd = aux[e];
                if (dd < 0) continue;
                float v = acc[rb][cb][reg] + bv;
                if (mode) atomicAdd(&msum[(size_t)dd * 128 + d], v);
                else      M[(size_t)dd * 128 + d] = f2bf(v);
            }
        }
    }
}

// ---------------- segment reduce: sum each node's contiguous M rows -> fp32 msum ----------------
__global__ __launch_bounds__(256) void reduce_seg(
    const unsigned short* __restrict__ M, const int* __restrict__ start,
    float* __restrict__ msum, int N)
{
    int node = blockIdx.x * 2 + (threadIdx.x >> 7);
    int d = threadIdx.x & 127;
    if (node >= N) return;
    int s = start[node], e = start[node + 1];
    float acc = 0.f;
    for (int r = s; r < e; ++r) acc += bf2f(M[(size_t)r * 128 + d]);
    msum[(size_t)node * 128 + d] = acc;
}

// ---------------- fused GRU: 32 nodes/block, all 512 gate cols, K=256, no G buffer ----------------
__global__ __launch_bounds__(256) void gru_fused(
    const float* __restrict__ msum, const unsigned short* __restrict__ hbf,
    const unsigned short* __restrict__ wcat, const float* __restrict__ bih,
    const float* __restrict__ bhh, const float* __restrict__ hf,
    float* __restrict__ out, int N)
{
    __shared__ unsigned short As[32][264];   // [node][k]: k<128 = m (bf16 of msum), k>=128 = h
    __shared__ unsigned short Bs[512][40];   // wcat k-chunk

    int tx = threadIdx.x;
    int n0 = blockIdx.x * 32;

    for (int f = tx; f < 1024; f += 256) {
        int row = f >> 5, c4 = (f & 31) * 4;
        int n = n0 + row; if (n >= N) n = N - 1;
        float4 v = *(const float4*)&msum[(size_t)n * 128 + c4];
        As[row][c4 + 0] = f2bf(v.x); As[row][c4 + 1] = f2bf(v.y);
        As[row][c4 + 2] = f2bf(v.z); As[row][c4 + 3] = f2bf(v.w);
    }
    for (int f = tx; f < 512; f += 256) {
        int row = f >> 4, c8 = (f & 15) * 8;
        int n = n0 + row; if (n >= N) n = N - 1;
        *(uint4*)&As[row][128 + c8] = *(const uint4*)&hbf[(size_t)n * 128 + c8];
    }

    int lane = tx & 63, w = tx >> 6;
    int rt = w & 1, cg = w >> 1;     // row tile (of 2), col group (of 2)
    int lr = lane & 15, quad = lane >> 4;
    f32x4 acc[4][4] = {};            // [gate][cb]

    for (int kc = 0; kc < 8; ++kc) {
        __syncthreads();
        for (int f = tx; f < 2048; f += 256) {
            int c = f >> 2, c8 = (f & 3) * 8;
            *(uint4*)&Bs[c][c8] = *(const uint4*)&wcat[(size_t)c * 256 + kc * 32 + c8];
        }
        __syncthreads();
        bf16x8 af = *(const bf16x8*)&As[rt * 16 + lr][kc * 32 + quad * 8];
        #pragma unroll
        for (int g = 0; g < 4; ++g)
            #pragma unroll
            for (int cb = 0; cb < 4; ++cb) {
                bf16x8 bf = *(const bf16x8*)&Bs[g * 128 + cg * 64 + cb * 16 + lr][quad * 8];
                acc[g][cb] = __builtin_amdgcn_mfma_f32_16x16x32_bf16(af, bf, acc[g][cb], 0, 0, 0);
            }
    }

    #pragma unroll
    for (int cb = 0; cb < 4; ++cb) {
        int d = cg * 64 + cb * 16 + lr;           // within-gate column
        float b_r  = bih[d] + bhh[d];
        float b_z  = bih[128 + d] + bhh[128 + d];
        float b_in = bih[256 + d];
        float b_hn = bhh[256 + d];
        #pragma unroll
        for (int reg = 0; reg < 4; ++reg) {
            int n = n0 + rt * 16 + quad * 4 + reg;
            if (n >= N) continue;
            float r  = 1.f / (1.f + __expf(-(acc[0][cb][reg] + b_r)));
            float z  = 1.f / (1.f + __expf(-(acc[1][cb][reg] + b_z)));
            float nn = tanhf(acc[2][cb][reg] + b_in + r * (acc[3][cb][reg] + b_hn));
            float h0 = hf[(size_t)n * 128 + d];
            out[(size_t)n * 128 + d] = (1.f - z) * nn + z * h0;
        }
    }
}

extern "C" void kernel_launch(void* const* d_in, const int* in_sizes, int n_in,
                              void* d_out, int out_size, void* d_ws, size_t ws_size,
                              hipStream_t stream)
{
    const float* h     = (const float*)d_in[0];
    const int*   ei    = (const int*)d_in[1];
    const int*   etype = (const int*)d_in[2];
    const float* W     = (const float*)d_in[3];
    const float* b     = (const float*)d_in[4];
    const float* wih   = (const float*)d_in[5];
    const float* whh   = (const float*)d_in[6];
    const float* bih   = (const float*)d_in[7];
    const float* bhh   = (const float*)d_in[8];
    float* out = (float*)d_out;

    int E = in_sizes[1] / 2;
    int N = in_sizes[0] / HID;
    int capE = ((E + 127) / 128 + NTY) * 128;

    char* p = (char*)d_ws;
    auto alloc = [&](size_t bytes) { char* r = p; p += (bytes + 255) & ~(size_t)255; return r; };
    // base (both paths): ~29 MB
    unsigned short* hbf  = (unsigned short*)alloc((size_t)N * 128 * 2);
    unsigned short* WbfT = (unsigned short*)alloc((size_t)8 * 128 * 128 * 2);
    unsigned short* wcat = (unsigned short*)alloc((size_t)512 * 256 * 2);
    int* tcnt    = (int*)alloc(NTY * 4);
    int* tcur    = (int*)alloc(NTY * 4);
    int* sortedT = (int*)alloc((size_t)capE * 4);
    // fast-path extras: ~157 MB
    unsigned short* M = (unsigned short*)alloc((size_t)E * 128 * 2);
    int* q     = (int*)alloc((size_t)E * 4);
    int* deg   = (int*)alloc((size_t)N * 4);
    int* start = (int*)alloc((size_t)(N + 1) * 4);
    int* dcur  = (int*)alloc((size_t)N * 4);
    int* bsum  = (int*)alloc(512 * 4);
    int mode = ((size_t)(p - (char*)d_ws) <= ws_size) ? 0 : 1;   // 0 = sorted-M path, 1 = atomic fallback

    hipMemsetAsync(tcnt, 0, NTY * 4, stream);
    hipMemsetAsync(sortedT, 0xFF, (size_t)capE * 4, stream);
    if (mode == 0) hipMemsetAsync(deg, 0, (size_t)N * 4, stream);
    else           hipMemsetAsync(out, 0, (size_t)N * 128 * 4, stream);   // msum accumulator

    conv_h_kernel<<<(N * 128 + 255) / 256, 256, 0, stream>>>(h, hbf, N * 128);
    conv_W_kernel<<<(8 * 128 * 128) / 256, 256, 0, stream>>>(W, WbfT);
    conv_wcat_kernel<<<(512 * 256) / 256, 256, 0, stream>>>(wih, whh, wcat);

    hist_kernel<<<1024, 256, 0, stream>>>(etype, ei, E, tcnt, (mode == 0) ? deg : nullptr);
    scan_type_kernel<<<1, 64, 0, stream>>>(tcnt, tcur);
    if (mode == 0) {
        int nbA = (N + 255) / 256;
        scanA_kernel<<<nbA, 256, 0, stream>>>(deg, start, bsum, N);
        scanB_kernel<<<1, 512, 0, stream>>>(bsum, nbA);
        scanC_kernel<<<nbA, 256, 0, stream>>>(start, bsum, dcur, N, E);
    }
    scatter_agg<<<256, 256, 0, stream>>>(etype, ei, E, tcur, dcur, sortedT, q, (mode == 0) ? 1 : 0);

    msg_gemm<<<capE / 128, 256, 0, stream>>>(hbf, ei, E, etype, WbfT, b, sortedT, q, M, out, mode);
    if (mode == 0)
        reduce_seg<<<(N + 1) / 2, 256, 0, stream>>>(M, start, out, N);
    // messages (fp32) now live in d_out; gru_fused reads its own 32 rows then overwrites them
    gru_fused<<<(N + 31) / 32, 256, 0, stream>>>(out, hbf, wcat, bih, bhh, h, out, N);
}

// Round 5
// 470.814 us; speedup vs baseline: 11.6750x; 1.2253x over previous
//
#include <hip/hip_runtime.h>

#define HID 128
#define NTY 8

typedef __attribute__((ext_vector_type(8))) short bf16x8;
typedef __attribute__((ext_vector_type(4))) float f32x4;

__device__ __forceinline__ unsigned short f2bf(float x) {
    unsigned u = __float_as_uint(x);
    u += 0x7FFF + ((u >> 16) & 1);          // RNE
    return (unsigned short)(u >> 16);
}
__device__ __forceinline__ float bf2f(unsigned short s) {
    return __uint_as_float(((unsigned)s) << 16);
}
__device__ __forceinline__ float sigmoidf_fast(float x) {
    return 1.f / (1.f + __expf(-x));
}
__device__ __forceinline__ float tanhf_fast(float x) {
    // 1 - 2/(1+e^{2x}): exact limits at +/-inf, no branches
    return 1.f - 2.f / (1.f + __expf(2.f * x));
}

// ---------------- dtype prep ----------------
__global__ void conv_h_kernel(const float* __restrict__ h, unsigned short* __restrict__ hbf, int n) {
    int i = blockIdx.x * 256 + threadIdx.x;
    if (i < n) hbf[i] = f2bf(h[i]);
}
// WbfT[t][d][k] = bf16(W[t][k][d])  (B^T layout for MFMA B-frag b128 reads)
__global__ void conv_W_kernel(const float* __restrict__ W, unsigned short* __restrict__ WbfT) {
    int i = blockIdx.x * 256 + threadIdx.x;   // 8*128*128
    int t = i >> 14, rem = i & 16383, d = rem >> 7, k = rem & 127;
    WbfT[(t << 14) + (d << 7) + k] = f2bf(W[(t << 14) + (k << 7) + d]);
}
// wpk[((kc*3+g3)*128 + d)*32 + kk]: per-kc-chunk compact gate weights.
// kc<4: K=m half, gates {r,z,in} from wih; kc>=4: K=h half, gates {r,z,hn} from whh.
// Fragment property: a 16x16x32 B-frag (16 cols x 32 k) is 1KB CONTIGUOUS here.
__global__ void conv_wpk_kernel(const float* __restrict__ wih, const float* __restrict__ whh,
                                unsigned short* __restrict__ wpk) {
    int i = blockIdx.x * 256 + threadIdx.x;   // 8*3*128*32 = 98304
    if (i >= 8 * 3 * 128 * 32) return;
    int kk = i & 31;
    int rest = i >> 5;
    int d = rest & 127;
    int rest2 = rest >> 7;        // kc*3+g3, < 24
    int g3 = rest2 % 3, kc = rest2 / 3;
    float v;
    if (kc < 4) v = wih[(g3 * 128 + d) * 128 + kc * 32 + kk];
    else        v = whh[(g3 * 128 + d) * 128 + (kc - 4) * 32 + kk];
    wpk[i] = f2bf(v);
}

// ---------------- sort bookkeeping ----------------
__global__ void hist_kernel(const int* __restrict__ etype, const int* __restrict__ ei,
                            int E, int* __restrict__ tcnt, int* __restrict__ deg) {
    __shared__ int lc[NTY];
    if (threadIdx.x < NTY) lc[threadIdx.x] = 0;
    __syncthreads();
    int stride = gridDim.x * blockDim.x;
    for (int i = blockIdx.x * blockDim.x + threadIdx.x; i < E; i += stride) {
        atomicAdd(&lc[etype[i]], 1);
        if (deg) atomicAdd(&deg[ei[E + i]], 1);
    }
    __syncthreads();
    if (threadIdx.x < NTY) atomicAdd(&tcnt[threadIdx.x], lc[threadIdx.x]);
}

__global__ void scan_type_kernel(const int* __restrict__ tcnt, int* __restrict__ tcur) {
    if (threadIdx.x == 0) {
        int off = 0;
        for (int t = 0; t < NTY; ++t) { tcur[t] = off; off += (tcnt[t] + 127) & ~127; }
    }
}

__global__ void scanA_kernel(const int* __restrict__ deg, int* __restrict__ start,
                             int* __restrict__ bsum, int N) {
    __shared__ int s[256];
    int i = blockIdx.x * 256 + threadIdx.x;
    int v = (i < N) ? deg[i] : 0;
    s[threadIdx.x] = v;
    __syncthreads();
    for (int off = 1; off < 256; off <<= 1) {
        int t = (threadIdx.x >= off) ? s[threadIdx.x - off] : 0;
        __syncthreads();
        s[threadIdx.x] += t;
        __syncthreads();
    }
    if (i < N) start[i] = s[threadIdx.x] - v;
    if (threadIdx.x == 255) bsum[blockIdx.x] = s[255];
}

__global__ void scanB_kernel(int* __restrict__ bsum, int nb) {
    __shared__ int s[512];
    int tx = threadIdx.x;
    int v = (tx < nb) ? bsum[tx] : 0;
    s[tx] = v;
    __syncthreads();
    for (int off = 1; off < 512; off <<= 1) {
        int t = (tx >= off) ? s[tx - off] : 0;
        __syncthreads();
        s[tx] += t;
        __syncthreads();
    }
    if (tx < nb) bsum[tx] = s[tx] - v;
}

__global__ void scanC_kernel(int* __restrict__ start, const int* __restrict__ bsum,
                             int* __restrict__ dcur, int N, int E) {
    int i = blockIdx.x * 256 + threadIdx.x;
    if (i < N) {
        int v = start[i] + bsum[blockIdx.x];
        start[i] = v;
        dcur[i] = v;
    }
    if (i == 0) start[N] = E;
}

// block-aggregated scatter: 8 global tcur atomics per BLOCK instead of per edge
__global__ __launch_bounds__(256) void scatter_agg(
    const int* __restrict__ etype, const int* __restrict__ ei, int E,
    int* __restrict__ tcur, int* __restrict__ dcur,
    int* __restrict__ sortedT, int* __restrict__ q, int mode)
{
    __shared__ int lcnt[NTY];
    __shared__ int lbase[NTY];
    int tx = threadIdx.x;
    int chunk = (E + gridDim.x - 1) / gridDim.x;
    int s = blockIdx.x * chunk;
    int e = s + chunk; if (e > E) e = E;
    if (tx < NTY) lcnt[tx] = 0;
    __syncthreads();
    for (int i = s + tx; i < e; i += 256)
        atomicAdd(&lcnt[etype[i]], 1);
    __syncthreads();
    if (tx < NTY) {
        lbase[tx] = atomicAdd(&tcur[tx], lcnt[tx]);   // reserve per-type range
        lcnt[tx] = 0;                                  // reuse as local cursor
    }
    __syncthreads();
    for (int i = s + tx; i < e; i += 256) {
        int t = etype[i];
        int lp = atomicAdd(&lcnt[t], 1);              // LDS atomic
        sortedT[lbase[t] + lp] = i;
        if (mode) q[i] = atomicAdd(&dcur[ei[E + i]], 1);  // 100k addrs, low contention
    }
}

// ---------------- msg GEMM: 128-edge x 128-d tile, bf16 MFMA ----------------
__global__ __launch_bounds__(256) void msg_gemm(
    const unsigned short* __restrict__ hbf, const int* __restrict__ ei, int E,
    const int* __restrict__ etype, const unsigned short* __restrict__ WbfT,
    const float* __restrict__ bias, const int* __restrict__ sortedT,
    const int* __restrict__ q, unsigned short* __restrict__ M,
    float* __restrict__ msum, int mode)
{
    __shared__ unsigned short hs[128][136];
    __shared__ unsigned short Bs[128][40];
    __shared__ int srcs[128], aux[128];
    __shared__ int stype;

    int tx = threadIdx.x;
    int base = blockIdx.x * 128;
    if (tx < 128) {
        int id = sortedT[base + tx];
        srcs[tx] = (id >= 0) ? ei[id] : -1;
        aux[tx]  = (id >= 0) ? (mode ? ei[E + id] : q[id]) : -1;
    }
    if (tx == 0) { int id0 = sortedT[base]; stype = (id0 >= 0) ? etype[id0] : -1; }
    __syncthreads();
    int t = stype;
    if (t < 0) return;

    const unsigned short* Wb = WbfT + (t << 14);

    for (int f = tx; f < 2048; f += 256) {
        int row = f >> 4, c8 = (f & 15) * 8;
        int s = srcs[row]; if (s < 0) s = 0;
        *(uint4*)&hs[row][c8] = *(const uint4*)&hbf[(size_t)s * 128 + c8];
    }

    int lane = tx & 63, w = tx >> 6;
    int r0 = (w >> 1) * 64, c0 = (w & 1) * 64;
    int lr = lane & 15, quad = lane >> 4;
    f32x4 acc[4][4] = {};

    for (int kc = 0; kc < 4; ++kc) {
        __syncthreads();
        for (int f = tx; f < 512; f += 256) {
            int d = f >> 2, c8 = (f & 3) * 8;
            *(uint4*)&Bs[d][c8] = *(const uint4*)&Wb[(d << 7) + kc * 32 + c8];
        }
        __syncthreads();
        bf16x8 af[4], bfr[4];
        #pragma unroll
        for (int rb = 0; rb < 4; ++rb) af[rb]  = *(const bf16x8*)&hs[r0 + rb * 16 + lr][kc * 32 + quad * 8];
        #pragma unroll
        for (int cb = 0; cb < 4; ++cb) bfr[cb] = *(const bf16x8*)&Bs[c0 + cb * 16 + lr][quad * 8];
        #pragma unroll
        for (int rb = 0; rb < 4; ++rb)
            #pragma unroll
            for (int cb = 0; cb < 4; ++cb)
                acc[rb][cb] = __builtin_amdgcn_mfma_f32_16x16x32_bf16(af[rb], bfr[cb], acc[rb][cb], 0, 0, 0);
    }

    #pragma unroll
    for (int cb = 0; cb < 4; ++cb) {
        int d = c0 + cb * 16 + lr;
        float bv = bias[t * 128 + d];
        #pragma unroll
        for (int rb = 0; rb < 4; ++rb) {
            #pragma unroll
            for (int reg = 0; reg < 4; ++reg) {
                int e = r0 + rb * 16 + quad * 4 + reg;
                int dd = aux[e];
                if (dd < 0) continue;
                float v = acc[rb][cb][reg] + bv;
                if (mode) atomicAdd(&msum[(size_t)dd * 128 + d], v);
                else      M[(size_t)dd * 128 + d] = f2bf(v);
            }
        }
    }
}

// ---------------- fused seg-reduce + GRU: 64 nodes/block, barrier-free K-loop ----------------
// A (LDS): [node][k] k<128 = sum of M segment (bf16), k>=128 = h (bf16).
// B: read per-MFMA-fragment straight from global wpk (1KB contiguous per frag, L1/L2-hot).
__global__ __launch_bounds__(256) void gru_fused(
    const unsigned short* __restrict__ M, const int* __restrict__ start,
    const float* __restrict__ msum_fb, const unsigned short* __restrict__ hbf,
    const unsigned short* __restrict__ wpk, const float* __restrict__ bih,
    const float* __restrict__ bhh, const float* __restrict__ hf,
    float* __restrict__ out, int N, int mode)
{
    __shared__ unsigned short As[64][264];

    int tx = threadIdx.x;
    int n0 = blockIdx.x * 64;

    // ---- stage A: 4 threads per node, fused segment reduce ----
    {
        int node = tx >> 2, qd = tx & 3;
        int n = n0 + node;
        int nc = (n < N) ? n : N - 1;
        float a[32];
        #pragma unroll
        for (int j = 0; j < 32; ++j) a[j] = 0.f;
        if (mode == 0) {
            int s = start[nc], e = start[nc + 1];
            for (int r = s; r < e; ++r) {
                #pragma unroll
                for (int j = 0; j < 4; ++j) {
                    uint4 v = *(const uint4*)&M[(size_t)r * 128 + qd * 32 + j * 8];
                    const unsigned short* pv = (const unsigned short*)&v;
                    #pragma unroll
                    for (int u = 0; u < 8; ++u) a[j * 8 + u] += bf2f(pv[u]);
                }
            }
        } else {
            #pragma unroll
            for (int j = 0; j < 8; ++j) {
                float4 v = *(const float4*)&msum_fb[(size_t)nc * 128 + qd * 32 + j * 4];
                a[j * 4 + 0] = v.x; a[j * 4 + 1] = v.y; a[j * 4 + 2] = v.z; a[j * 4 + 3] = v.w;
            }
        }
        unsigned short tmp[32];
        #pragma unroll
        for (int j = 0; j < 32; ++j) tmp[j] = f2bf(a[j]);
        #pragma unroll
        for (int j = 0; j < 4; ++j)
            *(uint4*)&As[node][qd * 32 + j * 8] = *(const uint4*)&tmp[j * 8];
        #pragma unroll
        for (int j = 0; j < 4; ++j)
            *(uint4*)&As[node][128 + qd * 32 + j * 8] =
                *(const uint4*)&hbf[(size_t)nc * 128 + qd * 32 + j * 8];
    }
    __syncthreads();

    // ---- MFMA: wave w -> rows rt*32..+31, cols cg*64..+63 of each gate ----
    int lane = tx & 63, w = tx >> 6;
    int rt = w & 1, cg = w >> 1;
    int lr = lane & 15, quad = lane >> 4;

    f32x4 aR[4][2] = {}, aZ[4][2] = {}, aI[4][2] = {}, aH[4][2] = {};

    #pragma unroll
    for (int kc = 0; kc < 4; ++kc) {      // K = m half: gates r,z,in
        bf16x8 af[2];
        #pragma unroll
        for (int r2 = 0; r2 < 2; ++r2)
            af[r2] = *(const bf16x8*)&As[rt * 32 + r2 * 16 + lr][kc * 32 + quad * 8];
        #pragma unroll
        for (int g3 = 0; g3 < 3; ++g3) {
            #pragma unroll
            for (int ct = 0; ct < 4; ++ct) {
                bf16x8 bf = *(const bf16x8*)&wpk[((size_t)((kc * 3 + g3) * 128) + cg * 64 + ct * 16 + lr) * 32 + quad * 8];
                #pragma unroll
                for (int r2 = 0; r2 < 2; ++r2) {
                    if (g3 == 0) aR[ct][r2] = __builtin_amdgcn_mfma_f32_16x16x32_bf16(af[r2], bf, aR[ct][r2], 0, 0, 0);
                    else if (g3 == 1) aZ[ct][r2] = __builtin_amdgcn_mfma_f32_16x16x32_bf16(af[r2], bf, aZ[ct][r2], 0, 0, 0);
                    else aI[ct][r2] = __builtin_amdgcn_mfma_f32_16x16x32_bf16(af[r2], bf, aI[ct][r2], 0, 0, 0);
                }
            }
        }
    }
    #pragma unroll
    for (int kc = 4; kc < 8; ++kc) {      // K = h half: gates r,z,hn
        bf16x8 af[2];
        #pragma unroll
        for (int r2 = 0; r2 < 2; ++r2)
            af[r2] = *(const bf16x8*)&As[rt * 32 + r2 * 16 + lr][kc * 32 + quad * 8];
        #pragma unroll
        for (int g3 = 0; g3 < 3; ++g3) {
            #pragma unroll
            for (int ct = 0; ct < 4; ++ct) {
                bf16x8 bf = *(const bf16x8*)&wpk[((size_t)((kc * 3 + g3) * 128) + cg * 64 + ct * 16 + lr) * 32 + quad * 8];
                #pragma unroll
                for (int r2 = 0; r2 < 2; ++r2) {
                    if (g3 == 0) aR[ct][r2] = __builtin_amdgcn_mfma_f32_16x16x32_bf16(af[r2], bf, aR[ct][r2], 0, 0, 0);
                    else if (g3 == 1) aZ[ct][r2] = __builtin_amdgcn_mfma_f32_16x16x32_bf16(af[r2], bf, aZ[ct][r2], 0, 0, 0);
                    else aH[ct][r2] = __builtin_amdgcn_mfma_f32_16x16x32_bf16(af[r2], bf, aH[ct][r2], 0, 0, 0);
                }
            }
        }
    }

    // ---- epilogue ----
    #pragma unroll
    for (int ct = 0; ct < 4; ++ct) {
        int d = cg * 64 + ct * 16 + lr;
        float b_r  = bih[d] + bhh[d];
        float b_z  = bih[128 + d] + bhh[128 + d];
        float b_in = bih[256 + d];
        float b_hn = bhh[256 + d];
        #pragma unroll
        for (int r2 = 0; r2 < 2; ++r2) {
            #pragma unroll
            for (int reg = 0; reg < 4; ++reg) {
                int n = n0 + rt * 32 + r2 * 16 + quad * 4 + reg;
                if (n >= N) continue;
                float r  = sigmoidf_fast(aR[ct][r2][reg] + b_r);
                float z  = sigmoidf_fast(aZ[ct][r2][reg] + b_z);
                float nn = tanhf_fast(aI[ct][r2][reg] + b_in + r * (aH[ct][r2][reg] + b_hn));
                float h0 = hf[(size_t)n * 128 + d];
                out[(size_t)n * 128 + d] = (1.f - z) * nn + z * h0;
            }
        }
    }
}

extern "C" void kernel_launch(void* const* d_in, const int* in_sizes, int n_in,
                              void* d_out, int out_size, void* d_ws, size_t ws_size,
                              hipStream_t stream)
{
    const float* h     = (const float*)d_in[0];
    const int*   ei    = (const int*)d_in[1];
    const int*   etype = (const int*)d_in[2];
    const float* W     = (const float*)d_in[3];
    const float* b     = (const float*)d_in[4];
    const float* wih   = (const float*)d_in[5];
    const float* whh   = (const float*)d_in[6];
    const float* bih   = (const float*)d_in[7];
    const float* bhh   = (const float*)d_in[8];
    float* out = (float*)d_out;

    int E = in_sizes[1] / 2;
    int N = in_sizes[0] / HID;
    int capE = ((E + 127) / 128 + NTY) * 128;

    char* p = (char*)d_ws;
    auto alloc = [&](size_t bytes) { char* r = p; p += (bytes + 255) & ~(size_t)255; return r; };
    // base (both paths): ~29 MB
    unsigned short* hbf  = (unsigned short*)alloc((size_t)N * 128 * 2);
    unsigned short* WbfT = (unsigned short*)alloc((size_t)8 * 128 * 128 * 2);
    unsigned short* wpk  = (unsigned short*)alloc((size_t)8 * 3 * 128 * 32 * 2);
    int* tcnt    = (int*)alloc(NTY * 4);
    int* tcur    = (int*)alloc(NTY * 4);
    int* sortedT = (int*)alloc((size_t)capE * 4);
    // fast-path extras: ~157 MB
    unsigned short* M = (unsigned short*)alloc((size_t)E * 128 * 2);
    int* q     = (int*)alloc((size_t)E * 4);
    int* deg   = (int*)alloc((size_t)N * 4);
    int* start = (int*)alloc((size_t)(N + 1) * 4);
    int* dcur  = (int*)alloc((size_t)N * 4);
    int* bsum  = (int*)alloc(512 * 4);
    int mode = ((size_t)(p - (char*)d_ws) <= ws_size) ? 0 : 1;   // 0 = sorted-M path, 1 = atomic fallback

    hipMemsetAsync(tcnt, 0, NTY * 4, stream);
    hipMemsetAsync(sortedT, 0xFF, (size_t)capE * 4, stream);
    if (mode == 0) hipMemsetAsync(deg, 0, (size_t)N * 4, stream);
    else           hipMemsetAsync(out, 0, (size_t)N * 128 * 4, stream);   // msum accumulator

    conv_h_kernel<<<(N * 128 + 255) / 256, 256, 0, stream>>>(h, hbf, N * 128);
    conv_W_kernel<<<(8 * 128 * 128) / 256, 256, 0, stream>>>(W, WbfT);
    conv_wpk_kernel<<<(8 * 3 * 128 * 32 + 255) / 256, 256, 0, stream>>>(wih, whh, wpk);

    hist_kernel<<<1024, 256, 0, stream>>>(etype, ei, E, tcnt, (mode == 0) ? deg : nullptr);
    scan_type_kernel<<<1, 64, 0, stream>>>(tcnt, tcur);
    if (mode == 0) {
        int nbA = (N + 255) / 256;
        scanA_kernel<<<nbA, 256, 0, stream>>>(deg, start, bsum, N);
        scanB_kernel<<<1, 512, 0, stream>>>(bsum, nbA);
        scanC_kernel<<<nbA, 256, 0, stream>>>(start, bsum, dcur, N, E);
    }
    scatter_agg<<<256, 256, 0, stream>>>(etype, ei, E, tcur, dcur, sortedT, q, (mode == 0) ? 1 : 0);

    msg_gemm<<<capE / 128, 256, 0, stream>>>(hbf, ei, E, etype, WbfT, b, sortedT, q, M, out, mode);
    // gru reads M segments directly (fused reduce); in mode1 it reads msum from out
    gru_fused<<<(N + 63) / 64, 256, 0, stream>>>(M, start, out, hbf, wpk, bih, bhh, h, out, N, mode);
}

// Round 6
// 412.361 us; speedup vs baseline: 13.3300x; 1.1418x over previous
//
#include <hip/hip_runtime.h>

#define HID 128
#define NTY 8

typedef __attribute__((ext_vector_type(8))) short bf16x8;
typedef __attribute__((ext_vector_type(4))) float f32x4;

__device__ __forceinline__ unsigned short f2bf(float x) {
    unsigned u = __float_as_uint(x);
    u += 0x7FFF + ((u >> 16) & 1);          // RNE
    return (unsigned short)(u >> 16);
}
__device__ __forceinline__ float bf2f(unsigned short s) {
    return __uint_as_float(((unsigned)s) << 16);
}
__device__ __forceinline__ float sigmoidf_fast(float x) {
    return 1.f / (1.f + __expf(-x));
}
__device__ __forceinline__ float tanhf_fast(float x) {
    return 1.f - 2.f / (1.f + __expf(2.f * x));
}

// ---------------- dtype prep ----------------
__global__ void conv_h_kernel(const float* __restrict__ h, unsigned short* __restrict__ hbf, int n) {
    int i = blockIdx.x * 256 + threadIdx.x;
    if (i < n) hbf[i] = f2bf(h[i]);
}
// WbfT[t][d][k] = bf16(W[t][k][d])
__global__ void conv_W_kernel(const float* __restrict__ W, unsigned short* __restrict__ WbfT) {
    int i = blockIdx.x * 256 + threadIdx.x;   // 8*128*128
    int t = i >> 14, rem = i & 16383, d = rem >> 7, k = rem & 127;
    WbfT[(t << 14) + (d << 7) + k] = f2bf(W[(t << 14) + (k << 7) + d]);
}
// wpk[((kc*3+g3)*128 + d)*32 + kk]: per-kc-chunk compact gate weights.
__global__ void conv_wpk_kernel(const float* __restrict__ wih, const float* __restrict__ whh,
                                unsigned short* __restrict__ wpk) {
    int i = blockIdx.x * 256 + threadIdx.x;   // 8*3*128*32 = 98304
    if (i >= 8 * 3 * 128 * 32) return;
    int kk = i & 31;
    int rest = i >> 5;
    int d = rest & 127;
    int rest2 = rest >> 7;
    int g3 = rest2 % 3, kc = rest2 / 3;
    float v;
    if (kc < 4) v = wih[(g3 * 128 + d) * 128 + kc * 32 + kk];
    else        v = whh[(g3 * 128 + d) * 128 + (kc - 4) * 32 + kk];
    wpk[i] = f2bf(v);
}

// ---------------- sort bookkeeping ----------------
__global__ void hist_kernel(const int* __restrict__ etype, const int* __restrict__ ei,
                            int E, int* __restrict__ tcnt, int* __restrict__ deg) {
    __shared__ int lc[NTY];
    if (threadIdx.x < NTY) lc[threadIdx.x] = 0;
    __syncthreads();
    int stride = gridDim.x * blockDim.x;
    for (int i = blockIdx.x * blockDim.x + threadIdx.x; i < E; i += stride) {
        atomicAdd(&lc[etype[i]], 1);
        if (deg) atomicAdd(&deg[ei[E + i]], 1);
    }
    __syncthreads();
    if (threadIdx.x < NTY) atomicAdd(&tcnt[threadIdx.x], lc[threadIdx.x]);
}

__global__ void scan_type_kernel(const int* __restrict__ tcnt, int* __restrict__ tcur) {
    if (threadIdx.x == 0) {
        int off = 0;
        for (int t = 0; t < NTY; ++t) { tcur[t] = off; off += (tcnt[t] + 127) & ~127; }
    }
}

__global__ void scanA_kernel(const int* __restrict__ deg, int* __restrict__ start,
                             int* __restrict__ bsum, int N) {
    __shared__ int s[256];
    int i = blockIdx.x * 256 + threadIdx.x;
    int v = (i < N) ? deg[i] : 0;
    s[threadIdx.x] = v;
    __syncthreads();
    for (int off = 1; off < 256; off <<= 1) {
        int t = (threadIdx.x >= off) ? s[threadIdx.x - off] : 0;
        __syncthreads();
        s[threadIdx.x] += t;
        __syncthreads();
    }
    if (i < N) start[i] = s[threadIdx.x] - v;
    if (threadIdx.x == 255) bsum[blockIdx.x] = s[255];
}

__global__ void scanB_kernel(int* __restrict__ bsum, int nb) {
    __shared__ int s[512];
    int tx = threadIdx.x;
    int v = (tx < nb) ? bsum[tx] : 0;
    s[tx] = v;
    __syncthreads();
    for (int off = 1; off < 512; off <<= 1) {
        int t = (tx >= off) ? s[tx - off] : 0;
        __syncthreads();
        s[tx] += t;
        __syncthreads();
    }
    if (tx < nb) bsum[tx] = s[tx] - v;
}

__global__ void scanC_kernel(int* __restrict__ start, const int* __restrict__ bsum,
                             int* __restrict__ dcur, int N, int E) {
    int i = blockIdx.x * 256 + threadIdx.x;
    if (i < N) {
        int v = start[i] + bsum[blockIdx.x];
        start[i] = v;
        dcur[i] = v;
    }
    if (i == 0) start[N] = E;
}

// block-aggregated scatter: 8 global tcur atomics per BLOCK
__global__ __launch_bounds__(256) void scatter_agg(
    const int* __restrict__ etype, const int* __restrict__ ei, int E,
    int* __restrict__ tcur, int* __restrict__ dcur,
    int* __restrict__ sortedT, int* __restrict__ q, int mode)
{
    __shared__ int lcnt[NTY];
    __shared__ int lbase[NTY];
    int tx = threadIdx.x;
    int chunk = (E + gridDim.x - 1) / gridDim.x;
    int s = blockIdx.x * chunk;
    int e = s + chunk; if (e > E) e = E;
    if (tx < NTY) lcnt[tx] = 0;
    __syncthreads();
    for (int i = s + tx; i < e; i += 256)
        atomicAdd(&lcnt[etype[i]], 1);
    __syncthreads();
    if (tx < NTY) {
        lbase[tx] = atomicAdd(&tcur[tx], lcnt[tx]);
        lcnt[tx] = 0;
    }
    __syncthreads();
    for (int i = s + tx; i < e; i += 256) {
        int t = etype[i];
        int lp = atomicAdd(&lcnt[t], 1);
        sortedT[lbase[t] + lp] = i;
        if (mode) q[i] = atomicAdd(&dcur[ei[E + i]], 1);
    }
}

// ---------------- msg GEMM: 128-edge x 128-d tile, bf16 MFMA ----------------
// Operand-swapped MFMA: D[d][e] -> lane holds 4 CONSECUTIVE d (quad*4+reg),
// epilogue packs 4 bf16 into one 8B store (16 stores/lane vs 64 scattered 2B).
__global__ __launch_bounds__(256) void msg_gemm(
    const unsigned short* __restrict__ hbf, const int* __restrict__ ei, int E,
    const int* __restrict__ etype, const unsigned short* __restrict__ WbfT,
    const float* __restrict__ bias, const int* __restrict__ sortedT,
    const int* __restrict__ q, unsigned short* __restrict__ M,
    float* __restrict__ msum, int mode)
{
    __shared__ unsigned short hs[128][136];
    __shared__ unsigned short Bs[128][40];
    __shared__ int srcs[128], aux[128];
    __shared__ int stype;

    int tx = threadIdx.x;
    int base = blockIdx.x * 128;
    if (tx < 128) {
        int id = sortedT[base + tx];
        srcs[tx] = (id >= 0) ? ei[id] : -1;
        aux[tx]  = (id >= 0) ? (mode ? ei[E + id] : q[id]) : -1;
    }
    if (tx == 0) { int id0 = sortedT[base]; stype = (id0 >= 0) ? etype[id0] : -1; }
    __syncthreads();
    int t = stype;
    if (t < 0) return;

    const unsigned short* Wb = WbfT + (t << 14);

    for (int f = tx; f < 2048; f += 256) {
        int row = f >> 4, c8 = (f & 15) * 8;
        int s = srcs[row]; if (s < 0) s = 0;
        *(uint4*)&hs[row][c8] = *(const uint4*)&hbf[(size_t)s * 128 + c8];
    }

    int lane = tx & 63, w = tx >> 6;
    int r0 = (w >> 1) * 64, c0 = (w & 1) * 64;   // r0: edge-tile base, c0: d-tile base
    int lr = lane & 15, quad = lane >> 4;
    f32x4 acc[4][4] = {};   // [rb(e-tile)][cb(d-tile)], D[d][e] layout per tile

    for (int kc = 0; kc < 4; ++kc) {
        __syncthreads();
        for (int f = tx; f < 512; f += 256) {
            int d = f >> 2, c8 = (f & 3) * 8;
            *(uint4*)&Bs[d][c8] = *(const uint4*)&Wb[(d << 7) + kc * 32 + c8];
        }
        __syncthreads();
        bf16x8 af[4], bfr[4];
        #pragma unroll
        for (int rb = 0; rb < 4; ++rb) af[rb]  = *(const bf16x8*)&hs[r0 + rb * 16 + lr][kc * 32 + quad * 8];
        #pragma unroll
        for (int cb = 0; cb < 4; ++cb) bfr[cb] = *(const bf16x8*)&Bs[c0 + cb * 16 + lr][quad * 8];
        #pragma unroll
        for (int rb = 0; rb < 4; ++rb)
            #pragma unroll
            for (int cb = 0; cb < 4; ++cb)
                acc[rb][cb] = __builtin_amdgcn_mfma_f32_16x16x32_bf16(bfr[cb], af[rb], acc[rb][cb], 0, 0, 0);
    }

    // epilogue: D[d][e] -> e = r0+rb*16+lr (row), d = c0+cb*16+quad*4+reg (4 consecutive)
    float4 bv4[4];
    #pragma unroll
    for (int cb = 0; cb < 4; ++cb)
        bv4[cb] = *(const float4*)&bias[t * 128 + c0 + cb * 16 + quad * 4];

    #pragma unroll
    for (int rb = 0; rb < 4; ++rb) {
        int e = r0 + rb * 16 + lr;
        int mr = aux[e];
        if (mr < 0) continue;
        #pragma unroll
        for (int cb = 0; cb < 4; ++cb) {
            int d0 = c0 + cb * 16 + quad * 4;
            f32x4 a = acc[rb][cb];
            if (mode) {
                atomicAdd(&msum[(size_t)mr * 128 + d0 + 0], a[0] + bv4[cb].x);
                atomicAdd(&msum[(size_t)mr * 128 + d0 + 1], a[1] + bv4[cb].y);
                atomicAdd(&msum[(size_t)mr * 128 + d0 + 2], a[2] + bv4[cb].z);
                atomicAdd(&msum[(size_t)mr * 128 + d0 + 3], a[3] + bv4[cb].w);
            } else {
                uint2 v;
                v.x = (unsigned)f2bf(a[0] + bv4[cb].x) | ((unsigned)f2bf(a[1] + bv4[cb].y) << 16);
                v.y = (unsigned)f2bf(a[2] + bv4[cb].z) | ((unsigned)f2bf(a[3] + bv4[cb].w) << 16);
                *(uint2*)&M[(size_t)mr * 128 + d0] = v;
            }
        }
    }
}

// ---------------- fused seg-reduce + GRU: 64 nodes/block, barrier-free K-loop ----------------
// Operand-swapped MFMA: D[d][n] -> epilogue does coalesced float4 loads/stores.
__global__ __launch_bounds__(256) void gru_fused(
    const unsigned short* __restrict__ M, const int* __restrict__ start,
    const float* __restrict__ msum_fb, const unsigned short* __restrict__ hbf,
    const unsigned short* __restrict__ wpk, const float* __restrict__ bih,
    const float* __restrict__ bhh, const float* __restrict__ hf,
    float* __restrict__ out, int N, int mode)
{
    __shared__ unsigned short As[64][264];

    int tx = threadIdx.x;
    int n0 = blockIdx.x * 64;

    // ---- stage A: 4 threads per node, fused segment reduce ----
    {
        int node = tx >> 2, qd = tx & 3;
        int n = n0 + node;
        int nc = (n < N) ? n : N - 1;
        float a[32];
        #pragma unroll
        for (int j = 0; j < 32; ++j) a[j] = 0.f;
        if (mode == 0) {
            int s = start[nc], e = start[nc + 1];
            for (int r = s; r < e; ++r) {
                #pragma unroll
                for (int j = 0; j < 4; ++j) {
                    uint4 v = *(const uint4*)&M[(size_t)r * 128 + qd * 32 + j * 8];
                    const unsigned short* pv = (const unsigned short*)&v;
                    #pragma unroll
                    for (int u = 0; u < 8; ++u) a[j * 8 + u] += bf2f(pv[u]);
                }
            }
        } else {
            #pragma unroll
            for (int j = 0; j < 8; ++j) {
                float4 v = *(const float4*)&msum_fb[(size_t)nc * 128 + qd * 32 + j * 4];
                a[j * 4 + 0] = v.x; a[j * 4 + 1] = v.y; a[j * 4 + 2] = v.z; a[j * 4 + 3] = v.w;
            }
        }
        unsigned short tmp[32];
        #pragma unroll
        for (int j = 0; j < 32; ++j) tmp[j] = f2bf(a[j]);
        #pragma unroll
        for (int j = 0; j < 4; ++j)
            *(uint4*)&As[node][qd * 32 + j * 8] = *(const uint4*)&tmp[j * 8];
        #pragma unroll
        for (int j = 0; j < 4; ++j)
            *(uint4*)&As[node][128 + qd * 32 + j * 8] =
                *(const uint4*)&hbf[(size_t)nc * 128 + qd * 32 + j * 8];
    }
    __syncthreads();

    int lane = tx & 63, w = tx >> 6;
    int rt = w & 1, cg = w >> 1;
    int lr = lane & 15, quad = lane >> 4;

    f32x4 aR[4][2] = {}, aZ[4][2] = {}, aI[4][2] = {}, aH[4][2] = {};

    #pragma unroll
    for (int kc = 0; kc < 4; ++kc) {      // K = m half: gates r,z,in
        bf16x8 af[2];
        #pragma unroll
        for (int r2 = 0; r2 < 2; ++r2)
            af[r2] = *(const bf16x8*)&As[rt * 32 + r2 * 16 + lr][kc * 32 + quad * 8];
        #pragma unroll
        for (int g3 = 0; g3 < 3; ++g3) {
            #pragma unroll
            for (int ct = 0; ct < 4; ++ct) {
                bf16x8 bf = *(const bf16x8*)&wpk[((size_t)((kc * 3 + g3) * 128) + cg * 64 + ct * 16 + lr) * 32 + quad * 8];
                #pragma unroll
                for (int r2 = 0; r2 < 2; ++r2) {
                    if (g3 == 0) aR[ct][r2] = __builtin_amdgcn_mfma_f32_16x16x32_bf16(bf, af[r2], aR[ct][r2], 0, 0, 0);
                    else if (g3 == 1) aZ[ct][r2] = __builtin_amdgcn_mfma_f32_16x16x32_bf16(bf, af[r2], aZ[ct][r2], 0, 0, 0);
                    else aI[ct][r2] = __builtin_amdgcn_mfma_f32_16x16x32_bf16(bf, af[r2], aI[ct][r2], 0, 0, 0);
                }
            }
        }
    }
    #pragma unroll
    for (int kc = 4; kc < 8; ++kc) {      // K = h half: gates r,z,hn
        bf16x8 af[2];
        #pragma unroll
        for (int r2 = 0; r2 < 2; ++r2)
            af[r2] = *(const bf16x8*)&As[rt * 32 + r2 * 16 + lr][kc * 32 + quad * 8];
        #pragma unroll
        for (int g3 = 0; g3 < 3; ++g3) {
            #pragma unroll
            for (int ct = 0; ct < 4; ++ct) {
                bf16x8 bf = *(const bf16x8*)&wpk[((size_t)((kc * 3 + g3) * 128) + cg * 64 + ct * 16 + lr) * 32 + quad * 8];
                #pragma unroll
                for (int r2 = 0; r2 < 2; ++r2) {
                    if (g3 == 0) aR[ct][r2] = __builtin_amdgcn_mfma_f32_16x16x32_bf16(bf, af[r2], aR[ct][r2], 0, 0, 0);
                    else if (g3 == 1) aZ[ct][r2] = __builtin_amdgcn_mfma_f32_16x16x32_bf16(bf, af[r2], aZ[ct][r2], 0, 0, 0);
                    else aH[ct][r2] = __builtin_amdgcn_mfma_f32_16x16x32_bf16(bf, af[r2], aH[ct][r2], 0, 0, 0);
                }
            }
        }
    }

    // ---- epilogue: n = row (lr), d = 4 consecutive (quad*4+reg) -> float4 I/O ----
    #pragma unroll
    for (int ct = 0; ct < 4; ++ct) {
        int d0 = cg * 64 + ct * 16 + quad * 4;
        f32x4 bi_r = *(const f32x4*)&bih[d0];
        f32x4 bh_r = *(const f32x4*)&bhh[d0];
        f32x4 bi_z = *(const f32x4*)&bih[128 + d0];
        f32x4 bh_z = *(const f32x4*)&bhh[128 + d0];
        f32x4 bi_n = *(const f32x4*)&bih[256 + d0];
        f32x4 bh_n = *(const f32x4*)&bhh[256 + d0];
        #pragma unroll
        for (int r2 = 0; r2 < 2; ++r2) {
            int n = n0 + rt * 32 + r2 * 16 + lr;
            if (n >= N) continue;
            f32x4 h0 = *(const f32x4*)&hf[(size_t)n * 128 + d0];
            f32x4 o;
            #pragma unroll
            for (int j = 0; j < 4; ++j) {
                float r  = sigmoidf_fast(aR[ct][r2][j] + bi_r[j] + bh_r[j]);
                float z  = sigmoidf_fast(aZ[ct][r2][j] + bi_z[j] + bh_z[j]);
                float nn = tanhf_fast(aI[ct][r2][j] + bi_n[j] + r * (aH[ct][r2][j] + bh_n[j]));
                o[j] = (1.f - z) * nn + z * h0[j];
            }
            *(f32x4*)&out[(size_t)n * 128 + d0] = o;
        }
    }
}

extern "C" void kernel_launch(void* const* d_in, const int* in_sizes, int n_in,
                              void* d_out, int out_size, void* d_ws, size_t ws_size,
                              hipStream_t stream)
{
    const float* h     = (const float*)d_in[0];
    const int*   ei    = (const int*)d_in[1];
    const int*   etype = (const int*)d_in[2];
    const float* W     = (const float*)d_in[3];
    const float* b     = (const float*)d_in[4];
    const float* wih   = (const float*)d_in[5];
    const float* whh   = (const float*)d_in[6];
    const float* bih   = (const float*)d_in[7];
    const float* bhh   = (const float*)d_in[8];
    float* out = (float*)d_out;

    int E = in_sizes[1] / 2;
    int N = in_sizes[0] / HID;
    int capE = ((E + 127) / 128 + NTY) * 128;

    char* p = (char*)d_ws;
    auto alloc = [&](size_t bytes) { char* r = p; p += (bytes + 255) & ~(size_t)255; return r; };
    unsigned short* hbf  = (unsigned short*)alloc((size_t)N * 128 * 2);
    unsigned short* WbfT = (unsigned short*)alloc((size_t)8 * 128 * 128 * 2);
    unsigned short* wpk  = (unsigned short*)alloc((size_t)8 * 3 * 128 * 32 * 2);
    int* tcnt    = (int*)alloc(NTY * 4);
    int* tcur    = (int*)alloc(NTY * 4);
    int* sortedT = (int*)alloc((size_t)capE * 4);
    unsigned short* M = (unsigned short*)alloc((size_t)E * 128 * 2);
    int* q     = (int*)alloc((size_t)E * 4);
    int* deg   = (int*)alloc((size_t)N * 4);
    int* start = (int*)alloc((size_t)(N + 1) * 4);
    int* dcur  = (int*)alloc((size_t)N * 4);
    int* bsum  = (int*)alloc(512 * 4);
    int mode = ((size_t)(p - (char*)d_ws) <= ws_size) ? 0 : 1;

    hipMemsetAsync(tcnt, 0, NTY * 4, stream);
    hipMemsetAsync(sortedT, 0xFF, (size_t)capE * 4, stream);
    if (mode == 0) hipMemsetAsync(deg, 0, (size_t)N * 4, stream);
    else           hipMemsetAsync(out, 0, (size_t)N * 128 * 4, stream);

    conv_h_kernel<<<(N * 128 + 255) / 256, 256, 0, stream>>>(h, hbf, N * 128);
    conv_W_kernel<<<(8 * 128 * 128) / 256, 256, 0, stream>>>(W, WbfT);
    conv_wpk_kernel<<<(8 * 3 * 128 * 32 + 255) / 256, 256, 0, stream>>>(wih, whh, wpk);

    hist_kernel<<<1024, 256, 0, stream>>>(etype, ei, E, tcnt, (mode == 0) ? deg : nullptr);
    scan_type_kernel<<<1, 64, 0, stream>>>(tcnt, tcur);
    if (mode == 0) {
        int nbA = (N + 255) / 256;
        scanA_kernel<<<nbA, 256, 0, stream>>>(deg, start, bsum, N);
        scanB_kernel<<<1, 512, 0, stream>>>(bsum, nbA);
        scanC_kernel<<<nbA, 256, 0, stream>>>(start, bsum, dcur, N, E);
    }
    scatter_agg<<<256, 256, 0, stream>>>(etype, ei, E, tcur, dcur, sortedT, q, (mode == 0) ? 1 : 0);

    msg_gemm<<<capE / 128, 256, 0, stream>>>(hbf, ei, E, etype, WbfT, b, sortedT, q, M, out, mode);
    gru_fused<<<(N + 63) / 64, 256, 0, stream>>>(M, start, out, hbf, wpk, bih, bhh, h, out, N, mode);
}